// Round 7
// baseline (7479.802 us; speedup 1.0000x reference)
//
#include <hip/hip_runtime.h>

// RNN with feedback projection, MI355X persistent-kernel implementation, R8b.
// (R8 resubmission — R8 never ran: MI355X container failed twice, infra.)
// B=256, T=200, D_IN=512, UNITS=1024, PROJ=512.
//
// pre = [h | sigmoid(p) | x_t] @ [Wr; Wf; Wk] + bias  (K=2048)
// h   = tanh(pre) ;  p = h @ Wp + pb                  (K=1024)
//
// R7 post-mortem: cutting the per-wave serial load chain 4x was NULL
// (3322us ~= 3338us) -> latency models dead. Invariant across R2/R4/R7:
// TRANSACTION COUNT. Agent-scope atomic loads don't coalesce: each lane's
// u64 is one LLC transaction. 32 col-blocks re-reading full h+sigp = ~5.2M
// txns/step -> LLC small-txn throughput bound (~10-14us/step), explaining
// why chain length, issue pattern, and barrier design all changed nothing.
//
// R8: reduce txn count TOPOLOGICALLY, keeping the coherence-proven
// interleaved llc_load8->MFMA pattern frozen. 8 blocks/group (was 32):
// 64 blocks x 1024 threads (16 waves). Each block: 32 rows x 128 UNITS
// cols (phase A) and 64 PROJ cols (phase B); weights register-resident.
// Cross-block atomic traffic/step drops 6.7x; flags 4x.
// K-split across 16 waves exactly as R7 (waves 0-7 h, 8-11 sigp, 12-15 x).
// Publish/flag/poll protocol verbatim R4/R7. Reduction: 16 partials via
// 128KiB LDS in two rt-rounds; reduce waves = 8-15.

#define T_   200
#define DIN  512
#define U_   1024
#define P_   512

typedef _Float16 f16x8 __attribute__((ext_vector_type(8)));
typedef float    f32x4 __attribute__((ext_vector_type(4)));
typedef unsigned long long u64;

#define WPACK_ELEMS    2097152
#define WPPACK_ELEMS   524288
#define ABUFINIT_ELEMS 393216
#define WPACK_BYTES    4194304u
#define WPPACK_BYTES   1048576u
#define ABUF_BYTES     1572864u
#define AB_GROUP       98304      // f16 elems per group (2 bufs)
#define AB_BUF         49152      // f16 elems per buffer: [rt 2][ktg 48][lane 64][j 8]

// bars layout (unsigned):
//   [0..255]    barA[group][cb]   (h ready, value = t+1)   cb < 8 used
//   [256..511]  barB[group][cb]   (sigp ready, value = t+1)
#define BARS_WORDS 512

#define MFMA16(a, b, c) __builtin_amdgcn_mfma_f32_16x16x32_f16((a), (b), (c), 0, 0, 0)

__global__ __launch_bounds__(256) void prep_kernel(
    const float* __restrict__ krn, const float* __restrict__ rk,
    const float* __restrict__ fk, const float* __restrict__ pk,
    _Float16* __restrict__ Wpack, _Float16* __restrict__ Wppack,
    _Float16* __restrict__ Abuf, unsigned* __restrict__ bars)
{
  int n = blockIdx.x * 256 + threadIdx.x;
  if (blockIdx.x == 0) {
    for (int i = threadIdx.x; i < BARS_WORDS; i += 256) bars[i] = 0u;
  }

  if (n < WPACK_ELEMS) {
    // [cb 8][w 16][kt 4][ct 8][lane 64][j 8]
    // k = w*128 + kt*32 + ((lane>>4)<<3) + j ; col = cb*128 + ct*16 + (lane&15)
    int j = n & 7, lane = (n >> 3) & 63, ct = (n >> 9) & 7;
    int kt = (n >> 12) & 3, w = (n >> 14) & 15, cb = n >> 18;
    int k   = w * 128 + kt * 32 + ((lane >> 4) << 3) + j;
    int col = cb * 128 + ct * 16 + (lane & 15);
    float v;
    if (k < 1024)       v = rk[(size_t)k * 1024 + col];
    else if (k < 1536)  v = fk[(size_t)(k - 1024) * 1024 + col];
    else                v = krn[(size_t)(k - 1536) * 1024 + col];
    Wpack[n] = (_Float16)v;
    return;
  }
  n -= WPACK_ELEMS;
  if (n < WPPACK_ELEMS) {
    // [cb 8][w 16][kt 2][ct 4][lane 64][j 8]
    // k = w*64 + kt*32 + ((lane>>4)<<3) + j ; col = cb*64 + ct*16 + (lane&15)
    int j = n & 7, lane = (n >> 3) & 63, ct = (n >> 9) & 3;
    int kt = (n >> 11) & 1, w = (n >> 12) & 15, cb = n >> 16;
    int k   = w * 64 + kt * 32 + ((lane >> 4) << 3) + j;
    int col = cb * 64 + ct * 16 + (lane & 15);
    Wppack[n] = (_Float16)pk[(size_t)k * 512 + col];
    return;
  }
  n -= WPPACK_ELEMS;
  if (n < ABUFINIT_ELEMS) {
    // buf0 init per group: ktg<32 (h) -> 0 ; ktg 32..47 (sigp) -> sigmoid(0)=0.5
    int g = n / AB_BUF;
    int q = n % AB_BUF;
    int kt = (q >> 9) % 48;
    Abuf[(size_t)g * AB_GROUP + q] = (_Float16)((kt < 32) ? 0.0f : 0.5f);
  }
}

// ---- LLC-coherent (agent-scope, relaxed, no cache maintenance) primitives ----
// FROZEN: interleaved load->consume only (R3/R5/R6 all showed batch-hoisted
// variants read stale data on this HW).
__device__ __forceinline__ f16x8 llc_load8(const _Float16* p) {
  u64 lo = __hip_atomic_load((const u64*)p,     __ATOMIC_RELAXED, __HIP_MEMORY_SCOPE_AGENT);
  u64 hi = __hip_atomic_load((const u64*)p + 1, __ATOMIC_RELAXED, __HIP_MEMORY_SCOPE_AGENT);
  union { u64 u[2]; f16x8 v; } c; c.u[0] = lo; c.u[1] = hi; return c.v;
}
__device__ __forceinline__ void llc_store16(_Float16* p, f16x8 v) {
  union { f16x8 v; u64 u[2]; } c; c.v = v;
  __hip_atomic_store((u64*)p,     c.u[0], __ATOMIC_RELAXED, __HIP_MEMORY_SCOPE_AGENT);
  __hip_atomic_store((u64*)p + 1, c.u[1], __ATOMIC_RELAXED, __HIP_MEMORY_SCOPE_AGENT);
}

// per-wave: wait until all 8 flags of this group reach tgt (monotonic, no reset)
__device__ __forceinline__ void group_wait(const unsigned* fl, int l, unsigned tgt) {
  const unsigned* p = fl + (l & 7);
  for (;;) {
    unsigned v = tgt;
    if (l < 8) v = __hip_atomic_load(p, __ATOMIC_RELAXED, __HIP_MEMORY_SCOPE_AGENT);
    if (__all((int)(v >= tgt))) break;
    __builtin_amdgcn_s_sleep(1);
  }
}

__global__ __launch_bounds__(1024, 1) void rnn_main(
    const float* __restrict__ x, const float* __restrict__ bias,
    const float* __restrict__ pbias,
    const _Float16* __restrict__ Wpack, const _Float16* __restrict__ Wppack,
    _Float16* __restrict__ Abuf, unsigned* __restrict__ bars,
    float* __restrict__ out)
{
  __shared__ f32x4 red[16][8][64];     // 128 KiB cross-wave K-reduction
  __shared__ _Float16 hs[32][136];     // h tile staging (128 + 8 pad)
  __shared__ _Float16 ps[32][72];      // sigp tile staging (64 + 8 pad)

  const int bid = blockIdx.x;          // 64 blocks
  const int g   = bid & 7;             // batch group (32 rows)
  const int cb  = bid >> 3;            // 0..7: UNITS cols cb*128..+128, PROJ cols cb*64..+64
  const int tid = threadIdx.x;
  const int w   = tid >> 6;            // wave id = K-sixteenth
  const int l   = tid & 63;

  // register-resident weight fragments (fp16, MFMA B-operand layout)
  // phase A: wave w owns K in [w*128, +128): 4 kt x 8 ct fragments
  f16x8 wA[4][8];
#pragma unroll
  for (int kt = 0; kt < 4; ++kt)
#pragma unroll
    for (int ct = 0; ct < 8; ++ct)
      wA[kt][ct] = *(const f16x8*)(Wpack +
        (((((size_t)(cb * 16 + w) * 4 + kt) * 8 + ct) * 64 + l) << 3));
  // phase B: wave w owns K in [w*64, +64): 2 kt x 4 ct fragments
  f16x8 wP[2][4];
#pragma unroll
  for (int kt = 0; kt < 2; ++kt)
#pragma unroll
    for (int ct = 0; ct < 4; ++ct)
      wP[kt][ct] = *(const f16x8*)(Wppack +
        (((((size_t)(cb * 16 + w) * 2 + kt) * 4 + ct) * 64 + l) << 3));

  // reduce waves = 8..15; v = tile index within round
  const int v = w - 8;
  float biasv = 0.f, pbv = 0.f;
  if (w >= 8) {
    biasv = bias[cb * 128 + v * 16 + (l & 15)];          // phase-A tile ct = v
    pbv   = pbias[cb * 64 + (v & 3) * 16 + (l & 15)];    // phase-B tile ct = v&3
  }

  _Float16* abg  = Abuf + (size_t)g * AB_GROUP;
  unsigned* barA = bars + g * 32;
  unsigned* barB = bars + 256 + g * 32;

  // x-wave addressing (waves 12-15, q = w-12 owns x cols [q*128, +128))
  const float* xrow0 = x + (size_t)(g * 32 + (l & 15)) * T_ * DIN;
  const float* xrow1 = x + (size_t)(g * 32 + 16 + (l & 15)) * T_ * DIN;
  const int xco = (l >> 4) << 3;

  for (int t = 0; t < T_; ++t) {
    const _Float16* acur = abg + (size_t)(t & 1) * AB_BUF;
    _Float16* anxt       = abg + (size_t)((t & 1) ^ 1) * AB_BUF;

    // ---- consumer-side wait: waves 0..11 (h/sigp readers) poll barB >= t.
    // barB[Y]=t transitively implies barA>=t, so h(t-1) AND sigp(t-1) are
    // visible. Waves 12-15 read only x -> skip, overlapping x loads.
    if (w < 12 && t > 0) group_wait(barB, l, (unsigned)t);

    // ============ phase A: pre = [h|sigp|x] @ Wcomb ; h = tanh(pre+bias) ============
    f32x4 a0[8], a1[8];
#pragma unroll
    for (int c = 0; c < 8; ++c) { a0[c] = {0.f,0.f,0.f,0.f}; a1[c] = a0[c]; }
    if (w < 12) {
      // waves 0-7: h (ktg 0..31); waves 8-11: sigp (ktg 32..47), ktg = w*4+kt.
      // FROZEN R4 pattern: interleaved llc_load8 -> MFMA, one ktg at a time.
      const _Float16* pa = acur + (size_t)(w * 4) * 512 + (size_t)l * 8;
#pragma unroll
      for (int kt = 0; kt < 4; ++kt) {
        f16x8 fa0 = llc_load8(pa + (size_t)kt * 512);
        f16x8 fa1 = llc_load8(pa + (size_t)(48 + kt) * 512);
#pragma unroll
        for (int c = 0; c < 8; ++c) {
          a0[c] = MFMA16(fa0, wA[kt][c], a0[c]);
          a1[c] = MFMA16(fa1, wA[kt][c], a1[c]);
        }
      }
    } else {
      // waves 12-15: x (K 1536..2047, 128 per wave) — plain cached fp32 + cvt
      const int q = w - 12;
      const float* xp0 = xrow0 + (size_t)t * DIN + q * 128 + xco;
      const float* xp1 = xrow1 + (size_t)t * DIN + q * 128 + xco;
#pragma unroll
      for (int kt = 0; kt < 4; ++kt) {
        float4 u0 = *(const float4*)(xp0 + kt * 32);
        float4 u1 = *(const float4*)(xp0 + kt * 32 + 4);
        float4 v0 = *(const float4*)(xp1 + kt * 32);
        float4 v1 = *(const float4*)(xp1 + kt * 32 + 4);
        f16x8 fa0, fa1;
        fa0[0]=(_Float16)u0.x; fa0[1]=(_Float16)u0.y; fa0[2]=(_Float16)u0.z; fa0[3]=(_Float16)u0.w;
        fa0[4]=(_Float16)u1.x; fa0[5]=(_Float16)u1.y; fa0[6]=(_Float16)u1.z; fa0[7]=(_Float16)u1.w;
        fa1[0]=(_Float16)v0.x; fa1[1]=(_Float16)v0.y; fa1[2]=(_Float16)v0.z; fa1[3]=(_Float16)v0.w;
        fa1[4]=(_Float16)v1.x; fa1[5]=(_Float16)v1.y; fa1[6]=(_Float16)v1.z; fa1[7]=(_Float16)v1.w;
#pragma unroll
        for (int c = 0; c < 8; ++c) {
          a0[c] = MFMA16(fa0, wA[kt][c], a0[c]);
          a1[c] = MFMA16(fa1, wA[kt][c], a1[c]);
        }
      }
    }
    // ---- 16-partial reduction, two rt-rounds through red[16][8][64] ----
    // (red's last reads were phase-B reduce of step t-1, closed by SB2)
#pragma unroll
    for (int c = 0; c < 8; ++c) red[w][c][l] = a0[c];
    __syncthreads();                                     // SA1
    if (w >= 8) {        // tile (rt=0, ct=v)
      f32x4 s = red[0][v][l];
#pragma unroll
      for (int j = 1; j < 16; ++j) s += red[j][v][l];
#pragma unroll
      for (int i = 0; i < 4; ++i)
        hs[((l >> 4) << 2) + i][v * 16 + (l & 15)] = (_Float16)tanhf(s[i] + biasv);
    }
    __syncthreads();                                     // SA2
#pragma unroll
    for (int c = 0; c < 8; ++c) red[w][c][l] = a1[c];
    __syncthreads();                                     // SA3
    if (w >= 8) {        // tile (rt=1, ct=v)
      f32x4 s = red[0][v][l];
#pragma unroll
      for (int j = 1; j < 16; ++j) s += red[j][v][l];
#pragma unroll
      for (int i = 0; i < 4; ++i)
        hs[16 + ((l >> 4) << 2) + i][v * 16 + (l & 15)] = (_Float16)tanhf(s[i] + biasv);
    }
    __syncthreads();                                     // SA4
    // wave 0 publishes h (2 rt x 4 ktg x 16B per lane): store, drain, flag
    if (tid < 64) {
      const int row16 = l & 15, o = l >> 4;
#pragma unroll
      for (int rt = 0; rt < 2; ++rt)
#pragma unroll
        for (int kk = 0; kk < 4; ++kk) {
          f16x8 tmp;
#pragma unroll
          for (int jj = 0; jj < 8; ++jj)
            tmp[jj] = hs[rt * 16 + row16][kk * 32 + o * 8 + jj];
          llc_store16(anxt + (size_t)(rt * 48 + cb * 4 + kk) * 512
                           + (size_t)(((o << 4) | row16) * 8), tmp);
        }
      asm volatile("" ::: "memory");
      __builtin_amdgcn_s_waitcnt(0);            // h committed at LLC
      asm volatile("" ::: "memory");
      if (tid == 0)
        __hip_atomic_store(barA + cb, (unsigned)(t + 1),
                           __ATOMIC_RELAXED, __HIP_MEMORY_SCOPE_AGENT);
      asm volatile("" ::: "memory");
    }
    // ALL waves poll h readiness themselves
    group_wait(barA, l, (unsigned)(t + 1));

    // ================= phase B: p = h @ Wp + pb ; sigp = sigmoid(p) =================
    f32x4 b0[4], b1[4];
#pragma unroll
    for (int c = 0; c < 4; ++c) { b0[c] = {0.f,0.f,0.f,0.f}; b1[c] = b0[c]; }
    {
      const _Float16* hb = anxt + (size_t)(w * 2) * 512 + (size_t)l * 8;
#pragma unroll
      for (int kt = 0; kt < 2; ++kt) {
        f16x8 h0 = llc_load8(hb + (size_t)kt * 512);
        f16x8 h1 = llc_load8(hb + (size_t)(48 + kt) * 512);
#pragma unroll
        for (int c = 0; c < 4; ++c) {
          b0[c] = MFMA16(h0, wP[kt][c], b0[c]);
          b1[c] = MFMA16(h1, wP[kt][c], b1[c]);
        }
      }
    }
#pragma unroll
    for (int c = 0; c < 4; ++c) { red[w][c][l] = b0[c]; red[w][4 + c][l] = b1[c]; }
    __syncthreads();                                     // SB1
    if (w >= 8) {        // tile (rt=v>>2, ct=v&3) lives in red slot v
      f32x4 s = red[0][v][l];
#pragma unroll
      for (int j = 1; j < 16; ++j) s += red[j][v][l];
      const int pcol = cb * 64 + (v & 3) * 16 + (l & 15);
#pragma unroll
      for (int i = 0; i < 4; ++i) {
        const int grow = (v >> 2) * 16 + ((l >> 4) << 2) + i;
        float p = s[i] + pbv;
        out[((size_t)(g * 32 + grow) * T_ + t) * P_ + pcol] = p;
        ps[grow][(v & 3) * 16 + (l & 15)] = (_Float16)(1.0f / (1.0f + __expf(-p)));
      }
    }
    __syncthreads();                                     // SB2
    // wave 0 publishes sigp (2 rt x 2 ktg x 16B per lane): store, drain, flag
    if (tid < 64) {
      const int row16 = l & 15, o = l >> 4;
#pragma unroll
      for (int rt = 0; rt < 2; ++rt)
#pragma unroll
        for (int kk = 0; kk < 2; ++kk) {
          f16x8 tmp;
#pragma unroll
          for (int jj = 0; jj < 8; ++jj)
            tmp[jj] = ps[rt * 16 + row16][kk * 32 + o * 8 + jj];
          llc_store16(anxt + (size_t)(rt * 48 + 32 + cb * 2 + kk) * 512
                           + (size_t)(((o << 4) | row16) * 8), tmp);
        }
      asm volatile("" ::: "memory");
      __builtin_amdgcn_s_waitcnt(0);            // sigp committed at LLC
      asm volatile("" ::: "memory");
      if (tid == 0)
        __hip_atomic_store(barB + cb, (unsigned)(t + 1),
                           __ATOMIC_RELAXED, __HIP_MEMORY_SCOPE_AGENT);
      asm volatile("" ::: "memory");
    }
    // next iteration's loop-top poll (barB >= t+1) is the consumer-side wait
  }
}

extern "C" void kernel_launch(void* const* d_in, const int* in_sizes, int n_in,
                              void* d_out, int out_size, void* d_ws, size_t ws_size,
                              hipStream_t stream)
{
  const float* x    = (const float*)d_in[0];
  const float* krn  = (const float*)d_in[1];
  const float* rk   = (const float*)d_in[2];
  const float* fk   = (const float*)d_in[3];
  const float* pk   = (const float*)d_in[4];
  const float* bias = (const float*)d_in[5];
  const float* pb   = (const float*)d_in[6];
  float* out = (float*)d_out;

  char* ws = (char*)d_ws;
  _Float16* Wpack  = (_Float16*)(ws);
  _Float16* Wppack = (_Float16*)(ws + WPACK_BYTES);
  _Float16* Abuf   = (_Float16*)(ws + WPACK_BYTES + WPPACK_BYTES);
  unsigned* bars   = (unsigned*)(ws + WPACK_BYTES + WPPACK_BYTES + ABUF_BYTES);
  // ws use: 4 MiB + 1 MiB + 1.5 MiB + 2 KiB

  // pack weights (new [cb 8][w 16] layouts), init step-0 activation buffer,
  // zero barriers (harness re-poisons ws to 0xAA before each timed call)
  hipLaunchKernelGGL(prep_kernel, dim3(11776), dim3(256), 0, stream,
                     krn, rk, fk, pk, Wpack, Wppack, Abuf, bars);

  void* args[] = { (void*)&x, (void*)&bias, (void*)&pb, (void*)&Wpack, (void*)&Wppack,
                   (void*)&Abuf, (void*)&bars, (void*)&out };
  hipLaunchCooperativeKernel((void*)rnn_main, dim3(64), dim3(1024), args, 0, stream);
}

// Round 8
// 2400.710 us; speedup vs baseline: 3.1157x; 3.1157x over previous
//
#include <hip/hip_runtime.h>

// RNN with feedback projection, MI355X persistent-kernel implementation, R9.
// B=256, T=200, D_IN=512, UNITS=1024, PROJ=512.
//
// pre = [h | sigmoid(p) | x_t] @ [Wr; Wf; Wk] + bias  (K=2048)
// h   = tanh(pre) ;  p = h @ Wp + pb                  (K=1024)
//
// R8b post-mortem: 128-col tile spilled (VGPR demand ~270 > 128 cap for
// 16-wave workgroups, m69) -> FETCH 4.8GB of scratch re-reads, 7.4ms.
// Topology theory untested. Sharpened model: agent-scope activation reads
// = C x 768KB/step (C = col-blocks/group); R2/R4/R7 all C=32 -> 24.6MB/step
// through the LLC-direct load path ~= the invariant 16.6us/step.
//
// R9: C=16 spill-free. 128 blocks x 512 threads (8 waves -> 256 VGPR cap).
// Block = 32 rows x 64 UNITS cols (A) / 32 PROJ cols (B). Per wave:
// wA[8][4]=128 + wP[4][2]=32 + acc 48 + temps ~= 220 < 256. Agent traffic
// halves to 12.3MB/step. Load pattern (interleaved llc_load8->MFMA, FROZEN
// per R3/R5/R6 staleness law), publish/flag/poll protocol verbatim R4/R7.
// K-split over 8 waves: 0-3 h, 4-5 sigp, 6-7 x. 8-partial reduction (64KiB
// LDS). Phase-B reducers = waves 4-7 so wave0's publish drain excludes the
// out HBM stores.

#define T_   200
#define DIN  512
#define U_   1024
#define P_   512

typedef _Float16 f16x8 __attribute__((ext_vector_type(8)));
typedef float    f32x4 __attribute__((ext_vector_type(4)));
typedef unsigned long long u64;

#define WPACK_ELEMS    2097152
#define WPPACK_ELEMS   524288
#define ABUFINIT_ELEMS 393216
#define WPACK_BYTES    4194304u
#define WPPACK_BYTES   1048576u
#define ABUF_BYTES     1572864u
#define AB_GROUP       98304      // f16 elems per group (2 bufs)
#define AB_BUF         49152      // f16 elems per buffer: [rt 2][ktg 48][lane 64][j 8]

// bars layout (unsigned):
//   [0..255]    barA[group][cb]   (h ready, value = t+1)   cb < 16 used
//   [256..511]  barB[group][cb]   (sigp ready, value = t+1)
#define BARS_WORDS 512

#define MFMA16(a, b, c) __builtin_amdgcn_mfma_f32_16x16x32_f16((a), (b), (c), 0, 0, 0)

__global__ __launch_bounds__(256) void prep_kernel(
    const float* __restrict__ krn, const float* __restrict__ rk,
    const float* __restrict__ fk, const float* __restrict__ pk,
    _Float16* __restrict__ Wpack, _Float16* __restrict__ Wppack,
    _Float16* __restrict__ Abuf, unsigned* __restrict__ bars)
{
  int n = blockIdx.x * 256 + threadIdx.x;
  if (blockIdx.x == 0) {
    for (int i = threadIdx.x; i < BARS_WORDS; i += 256) bars[i] = 0u;
  }

  if (n < WPACK_ELEMS) {
    // [cb 16][w 8][kt 8][ct 4][lane 64][j 8]
    // k = w*256 + kt*32 + ((lane>>4)<<3) + j ; col = cb*64 + ct*16 + (lane&15)
    int j = n & 7, lane = (n >> 3) & 63, ct = (n >> 9) & 3;
    int kt = (n >> 11) & 7, w = (n >> 14) & 7, cb = n >> 17;
    int k   = w * 256 + kt * 32 + ((lane >> 4) << 3) + j;
    int col = cb * 64 + ct * 16 + (lane & 15);
    float v;
    if (k < 1024)       v = rk[(size_t)k * 1024 + col];
    else if (k < 1536)  v = fk[(size_t)(k - 1024) * 1024 + col];
    else                v = krn[(size_t)(k - 1536) * 1024 + col];
    Wpack[n] = (_Float16)v;
    return;
  }
  n -= WPACK_ELEMS;
  if (n < WPPACK_ELEMS) {
    // [cb 16][w 8][kt 4][ct 2][lane 64][j 8]
    // k = w*128 + kt*32 + ((lane>>4)<<3) + j ; col = cb*32 + ct*16 + (lane&15)
    int j = n & 7, lane = (n >> 3) & 63, ct = (n >> 9) & 1;
    int kt = (n >> 10) & 3, w = (n >> 12) & 7, cb = n >> 15;
    int k   = w * 128 + kt * 32 + ((lane >> 4) << 3) + j;
    int col = cb * 32 + ct * 16 + (lane & 15);
    Wppack[n] = (_Float16)pk[(size_t)k * 512 + col];
    return;
  }
  n -= WPPACK_ELEMS;
  if (n < ABUFINIT_ELEMS) {
    // buf0 init per group: ktg<32 (h) -> 0 ; ktg 32..47 (sigp) -> sigmoid(0)=0.5
    int g = n / AB_BUF;
    int q = n % AB_BUF;
    int kt = (q >> 9) % 48;
    Abuf[(size_t)g * AB_GROUP + q] = (_Float16)((kt < 32) ? 0.0f : 0.5f);
  }
}

// ---- LLC-coherent (agent-scope, relaxed, no cache maintenance) primitives ----
// FROZEN: interleaved load->consume only (R3/R5/R6 all showed batch-hoisted
// variants read stale data on this HW).
__device__ __forceinline__ f16x8 llc_load8(const _Float16* p) {
  u64 lo = __hip_atomic_load((const u64*)p,     __ATOMIC_RELAXED, __HIP_MEMORY_SCOPE_AGENT);
  u64 hi = __hip_atomic_load((const u64*)p + 1, __ATOMIC_RELAXED, __HIP_MEMORY_SCOPE_AGENT);
  union { u64 u[2]; f16x8 v; } c; c.u[0] = lo; c.u[1] = hi; return c.v;
}
__device__ __forceinline__ void llc_store16(_Float16* p, f16x8 v) {
  union { f16x8 v; u64 u[2]; } c; c.v = v;
  __hip_atomic_store((u64*)p,     c.u[0], __ATOMIC_RELAXED, __HIP_MEMORY_SCOPE_AGENT);
  __hip_atomic_store((u64*)p + 1, c.u[1], __ATOMIC_RELAXED, __HIP_MEMORY_SCOPE_AGENT);
}

// per-wave: wait until all 16 flags of this group reach tgt (monotonic)
__device__ __forceinline__ void group_wait(const unsigned* fl, int l, unsigned tgt) {
  const unsigned* p = fl + (l & 15);
  for (;;) {
    unsigned v = tgt;
    if (l < 16) v = __hip_atomic_load(p, __ATOMIC_RELAXED, __HIP_MEMORY_SCOPE_AGENT);
    if (__all((int)(v >= tgt))) break;
    __builtin_amdgcn_s_sleep(1);
  }
}

__global__ __launch_bounds__(512, 2) void rnn_main(
    const float* __restrict__ x, const float* __restrict__ bias,
    const float* __restrict__ pbias,
    const _Float16* __restrict__ Wpack, const _Float16* __restrict__ Wppack,
    _Float16* __restrict__ Abuf, unsigned* __restrict__ bars,
    float* __restrict__ out)
{
  __shared__ f32x4 red[8][8][64];      // 64 KiB cross-wave K-reduction
  __shared__ _Float16 hs[32][72];      // h tile staging (64 + 8 pad)
  __shared__ _Float16 ps[32][40];      // sigp tile staging (32 + 8 pad)

  const int bid = blockIdx.x;          // 128 blocks
  const int g   = bid & 7;             // batch group (32 rows)
  const int cb  = bid >> 3;            // 0..15: UNITS cols cb*64..+64, PROJ cols cb*32..+32
  const int tid = threadIdx.x;
  const int w   = tid >> 6;            // wave id = K-eighth
  const int l   = tid & 63;

  // register-resident weight fragments (fp16, MFMA B-operand layout)
  // phase A: wave w owns K in [w*256, +256): 8 kt x 4 ct fragments (128 VGPR)
  f16x8 wA[8][4];
#pragma unroll
  for (int kt = 0; kt < 8; ++kt)
#pragma unroll
    for (int ct = 0; ct < 4; ++ct)
      wA[kt][ct] = *(const f16x8*)(Wpack +
        (((((size_t)(cb * 8 + w) * 8 + kt) * 4 + ct) * 64 + l) << 3));
  // phase B: wave w owns K in [w*128, +128): 4 kt x 2 ct fragments (32 VGPR)
  f16x8 wP[4][2];
#pragma unroll
  for (int kt = 0; kt < 4; ++kt)
#pragma unroll
    for (int ct = 0; ct < 2; ++ct)
      wP[kt][ct] = *(const f16x8*)(Wppack +
        (((((size_t)(cb * 8 + w) * 4 + kt) * 2 + ct) * 64 + l) << 3));

  // phase-A reduce: wave w owns tile (rtA = w>>2, ctA = w&3)
  const int rtA = w >> 2, ctA = w & 3;
  const float biasv = bias[cb * 64 + ctA * 16 + (l & 15)];
  // phase-B reduce: waves 4-7, vB = w-4 owns tile (rtB = vB>>1, ctB = vB&1)
  const int vB = w - 4;
  float pbv = 0.f;
  if (w >= 4) pbv = pbias[cb * 32 + (vB & 1) * 16 + (l & 15)];

  _Float16* abg  = Abuf + (size_t)g * AB_GROUP;
  unsigned* barA = bars + g * 32;
  unsigned* barB = bars + 256 + g * 32;

  // x-wave addressing (waves 6-7, q = w-6 owns x cols [q*256, +256))
  const float* xrow0 = x + (size_t)(g * 32 + (l & 15)) * T_ * DIN;
  const float* xrow1 = x + (size_t)(g * 32 + 16 + (l & 15)) * T_ * DIN;
  const int xco = (l >> 4) << 3;

  for (int t = 0; t < T_; ++t) {
    const _Float16* acur = abg + (size_t)(t & 1) * AB_BUF;
    _Float16* anxt       = abg + (size_t)((t & 1) ^ 1) * AB_BUF;

    // ---- consumer-side wait: waves 0..5 (h/sigp readers) poll barB >= t.
    // barB[Y]=t transitively implies barA>=t, so h(t-1) AND sigp(t-1) are
    // visible. Waves 6-7 read only x -> skip, overlapping x loads.
    if (w < 6 && t > 0) group_wait(barB, l, (unsigned)t);

    // ============ phase A: pre = [h|sigp|x] @ Wcomb ; h = tanh(pre+bias) ============
    f32x4 a0[4], a1[4];
#pragma unroll
    for (int c = 0; c < 4; ++c) { a0[c] = {0.f,0.f,0.f,0.f}; a1[c] = a0[c]; }
    if (w < 6) {
      // waves 0-3: h (ktg 0..31); waves 4-5: sigp (ktg 32..47); ktg = w*8+kt.
      // FROZEN R4 pattern: interleaved llc_load8 -> MFMA, one ktg at a time.
      const _Float16* pa = acur + (size_t)(w * 8) * 512 + (size_t)l * 8;
#pragma unroll
      for (int kt = 0; kt < 8; ++kt) {
        f16x8 fa0 = llc_load8(pa + (size_t)kt * 512);
        f16x8 fa1 = llc_load8(pa + (size_t)(48 + kt) * 512);
#pragma unroll
        for (int c = 0; c < 4; ++c) {
          a0[c] = MFMA16(fa0, wA[kt][c], a0[c]);
          a1[c] = MFMA16(fa1, wA[kt][c], a1[c]);
        }
      }
    } else {
      // waves 6-7: x (K 1536..2047, 256 per wave) — plain cached fp32 + cvt
      const int q = w - 6;
      const float* xp0 = xrow0 + (size_t)t * DIN + q * 256 + xco;
      const float* xp1 = xrow1 + (size_t)t * DIN + q * 256 + xco;
#pragma unroll
      for (int kt = 0; kt < 8; ++kt) {
        float4 u0 = *(const float4*)(xp0 + kt * 32);
        float4 u1 = *(const float4*)(xp0 + kt * 32 + 4);
        float4 v0 = *(const float4*)(xp1 + kt * 32);
        float4 v1 = *(const float4*)(xp1 + kt * 32 + 4);
        f16x8 fa0, fa1;
        fa0[0]=(_Float16)u0.x; fa0[1]=(_Float16)u0.y; fa0[2]=(_Float16)u0.z; fa0[3]=(_Float16)u0.w;
        fa0[4]=(_Float16)u1.x; fa0[5]=(_Float16)u1.y; fa0[6]=(_Float16)u1.z; fa0[7]=(_Float16)u1.w;
        fa1[0]=(_Float16)v0.x; fa1[1]=(_Float16)v0.y; fa1[2]=(_Float16)v0.z; fa1[3]=(_Float16)v0.w;
        fa1[4]=(_Float16)v1.x; fa1[5]=(_Float16)v1.y; fa1[6]=(_Float16)v1.z; fa1[7]=(_Float16)v1.w;
#pragma unroll
        for (int c = 0; c < 4; ++c) {
          a0[c] = MFMA16(fa0, wA[kt][c], a0[c]);
          a1[c] = MFMA16(fa1, wA[kt][c], a1[c]);
        }
      }
    }
    // ---- 8-partial reduction: slot = rt*4 + ct ----
#pragma unroll
    for (int c = 0; c < 4; ++c) { red[w][c][l] = a0[c]; red[w][4 + c][l] = a1[c]; }
    __syncthreads();                                     // SA1
    {
      // wave w reduces tile (rtA, ctA) = slot rtA*4+ctA, tanh, stage in LDS
      const int slot = rtA * 4 + ctA;
      f32x4 s = red[0][slot][l];
#pragma unroll
      for (int j = 1; j < 8; ++j) s += red[j][slot][l];
#pragma unroll
      for (int i = 0; i < 4; ++i)
        hs[rtA * 16 + ((l >> 4) << 2) + i][ctA * 16 + (l & 15)] =
            (_Float16)tanhf(s[i] + biasv);
    }
    __syncthreads();                                     // SA2
    // wave 0 publishes h (2 rt x 2 ktg x 16B per lane): store, drain, flag
    if (tid < 64) {
      const int row16 = l & 15, o = l >> 4;
#pragma unroll
      for (int rt = 0; rt < 2; ++rt)
#pragma unroll
        for (int kk = 0; kk < 2; ++kk) {
          f16x8 tmp;
#pragma unroll
          for (int jj = 0; jj < 8; ++jj)
            tmp[jj] = hs[rt * 16 + row16][kk * 32 + o * 8 + jj];
          llc_store16(anxt + (size_t)(rt * 48 + cb * 2 + kk) * 512
                           + (size_t)l * 8, tmp);
        }
      asm volatile("" ::: "memory");
      __builtin_amdgcn_s_waitcnt(0);            // h committed at LLC
      asm volatile("" ::: "memory");
      if (tid == 0)
        __hip_atomic_store(barA + cb, (unsigned)(t + 1),
                           __ATOMIC_RELAXED, __HIP_MEMORY_SCOPE_AGENT);
      asm volatile("" ::: "memory");
    }
    // ALL waves poll h readiness themselves
    group_wait(barA, l, (unsigned)(t + 1));

    // ================= phase B: p = h @ Wp + pb ; sigp = sigmoid(p) =================
    f32x4 b0[2], b1[2];
#pragma unroll
    for (int c = 0; c < 2; ++c) { b0[c] = {0.f,0.f,0.f,0.f}; b1[c] = b0[c]; }
    {
      // ktg = w*4 + kt (h tiles 0..31)
      const _Float16* hb = anxt + (size_t)(w * 4) * 512 + (size_t)l * 8;
#pragma unroll
      for (int kt = 0; kt < 4; ++kt) {
        f16x8 h0 = llc_load8(hb + (size_t)kt * 512);
        f16x8 h1 = llc_load8(hb + (size_t)(48 + kt) * 512);
#pragma unroll
        for (int c = 0; c < 2; ++c) {
          b0[c] = MFMA16(h0, wP[kt][c], b0[c]);
          b1[c] = MFMA16(h1, wP[kt][c], b1[c]);
        }
      }
    }
#pragma unroll
    for (int c = 0; c < 2; ++c) { red[w][c][l] = b0[c]; red[w][2 + c][l] = b1[c]; }
    __syncthreads();                                     // SB1
    if (w >= 4) {
      // wave vB reduces tile (rtB, ctB) = slot vB; +pb, out store, sigmoid->LDS
      f32x4 s = red[0][vB][l];
#pragma unroll
      for (int j = 1; j < 8; ++j) s += red[j][vB][l];
      const int pcol = cb * 32 + (vB & 1) * 16 + (l & 15);
#pragma unroll
      for (int i = 0; i < 4; ++i) {
        const int grow = (vB >> 1) * 16 + ((l >> 4) << 2) + i;
        float p = s[i] + pbv;
        out[((size_t)(g * 32 + grow) * T_ + t) * P_ + pcol] = p;
        ps[grow][(vB & 1) * 16 + (l & 15)] = (_Float16)(1.0f / (1.0f + __expf(-p)));
      }
    }
    __syncthreads();                                     // SB2
    // wave 0 publishes sigp (2 rt x 1 ktg x 16B per lane): store, drain, flag
    if (tid < 64) {
      const int row16 = l & 15, o = l >> 4;
#pragma unroll
      for (int rt = 0; rt < 2; ++rt) {
        f16x8 tmp;
#pragma unroll
        for (int jj = 0; jj < 8; ++jj)
          tmp[jj] = ps[rt * 16 + row16][o * 8 + jj];
        llc_store16(anxt + (size_t)(rt * 48 + 32 + cb) * 512
                         + (size_t)l * 8, tmp);
      }
      asm volatile("" ::: "memory");
      __builtin_amdgcn_s_waitcnt(0);            // sigp committed at LLC
      asm volatile("" ::: "memory");
      if (tid == 0)
        __hip_atomic_store(barB + cb, (unsigned)(t + 1),
                           __ATOMIC_RELAXED, __HIP_MEMORY_SCOPE_AGENT);
      asm volatile("" ::: "memory");
    }
    // next iteration's loop-top poll (barB >= t+1) is the consumer-side wait
  }
}

extern "C" void kernel_launch(void* const* d_in, const int* in_sizes, int n_in,
                              void* d_out, int out_size, void* d_ws, size_t ws_size,
                              hipStream_t stream)
{
  const float* x    = (const float*)d_in[0];
  const float* krn  = (const float*)d_in[1];
  const float* rk   = (const float*)d_in[2];
  const float* fk   = (const float*)d_in[3];
  const float* pk   = (const float*)d_in[4];
  const float* bias = (const float*)d_in[5];
  const float* pb   = (const float*)d_in[6];
  float* out = (float*)d_out;

  char* ws = (char*)d_ws;
  _Float16* Wpack  = (_Float16*)(ws);
  _Float16* Wppack = (_Float16*)(ws + WPACK_BYTES);
  _Float16* Abuf   = (_Float16*)(ws + WPACK_BYTES + WPPACK_BYTES);
  unsigned* bars   = (unsigned*)(ws + WPACK_BYTES + WPPACK_BYTES + ABUF_BYTES);
  // ws use: 4 MiB + 1 MiB + 1.5 MiB + 2 KiB

  // pack weights ([cb 16][w 8] layouts), init step-0 activation buffer,
  // zero barriers (harness re-poisons ws to 0xAA before each timed call)
  hipLaunchKernelGGL(prep_kernel, dim3(11776), dim3(256), 0, stream,
                     krn, rk, fk, pk, Wpack, Wppack, Abuf, bars);

  void* args[] = { (void*)&x, (void*)&bias, (void*)&pb, (void*)&Wpack, (void*)&Wppack,
                   (void*)&Abuf, (void*)&bars, (void*)&out };
  hipLaunchCooperativeKernel((void*)rnn_main, dim3(128), dim3(512), args, 0, stream);
}